// Round 22
// baseline (257.197 us; speedup 1.0000x reference)
//
#include <hip/hip_runtime.h>
#include <cstdint>
#include <cstddef>

// ---------------------------------------------------------------------------
// Adaptive log-softmax NLL. bf16 MFMA GEMMs fused with online logsumexp.
// R22: R21 (256.5us) + launch-graph squeeze: (1) last 24 head-BT panels
// transpose as FILLER inside the proj launch (k_proj_plus) -- hides ~9us of
// stage1 under proj's idle window; TJob gains ldw (stride != bound for the
// shifted-W job). (2) cvt+compact -> k_pre; cnt zeroed by hipMemsetAsync;
// tail kernels guard tl-writes with (m0+lrow < cntv) so trel tails need no
// init. Mega (XCD-swizzled) / tails / finalize unchanged.
// ---------------------------------------------------------------------------

typedef unsigned short u16;
typedef __attribute__((ext_vector_type(8))) __bf16 bf16x8;
typedef __attribute__((ext_vector_type(8))) u16 u16x8;
typedef __attribute__((ext_vector_type(4))) float f32x4;

#define AS1 __attribute__((address_space(1)))
#define AS3 __attribute__((address_space(3)))

__device__ __forceinline__ u16 f2bf(float f){
  union { float f; unsigned u; } v; v.f = f;
  unsigned r = v.u + 0x7fffu + ((v.u >> 16) & 1u);  // RNE
  return (u16)(r >> 16);
}
__device__ __forceinline__ void glds16(const void* g, void* l){
  __builtin_amdgcn_global_load_lds((AS1 unsigned*)(uintptr_t)g,
                                   (AS3 unsigned*)(unsigned)(uintptr_t)l, 16, 0, 0);
}

// ---------------- transpose job descriptors ----------------
struct TJob { const float* W; u16* BT; int K, N, ldw, Kpad, nrows, nx, base, blk; };
struct TJobs { TJob j[8]; int nj; };

template<int TPB>
__device__ __forceinline__ void transpose_tile(const TJobs& jobs, int id,
                                               float (*t)[65], int tid){
  int ji = 0;
  #pragma unroll
  for (int i = 1; i < 8; ++i)
    if (i < jobs.nj && id >= jobs.j[i].base) ji = i;
  TJob jb = jobs.j[ji];
  int local = id - jb.base;
  int bx = local % jb.nx;
  int by = local / jb.nx;

  const int n0 = bx * 64;
  const int k0 = by * 64;
  const bool al = (jb.N & 3) == 0;
  for (int i = tid; i < 64*16; i += TPB){
    int r = i >> 4, c4 = (i & 15) * 4;
    int k = k0 + r, n = n0 + c4;
    f32x4 v; v.x=0.f; v.y=0.f; v.z=0.f; v.w=0.f;
    if (k < jb.K){
      if (al && n + 3 < jb.N) v = *(const f32x4*)(jb.W + (size_t)k * jb.ldw + n);
      else { for (int q = 0; q < 4; ++q) if (n + q < jb.N) v[q] = jb.W[(size_t)k * jb.ldw + n + q]; }
    }
    t[r][c4] = v.x; t[r][c4+1] = v.y; t[r][c4+2] = v.z; t[r][c4+3] = v.w;
  }
  __syncthreads();
  for (int i = tid; i < 64*8; i += TPB){
    int rn = i >> 3, c8 = (i & 7) * 8;
    int n = n0 + rn;
    if (k0 + c8 < jb.Kpad && n < jb.nrows){
      u16x8 o;
      #pragma unroll
      for (int q = 0; q < 8; ++q) o[q] = f2bf(t[c8 + q][rn]);
      size_t off;
      if (jb.blk)
        off = (((size_t)(n >> 7) * (jb.Kpad >> 6) + (k0 >> 6)) * 128 + (n & 127)) * 64 + c8;
      else
        off = (size_t)n * jb.Kpad + k0 + c8;
      *(u16x8*)(jb.BT + off) = o;
    }
  }
}

// ---------------- pre: cvt_hidden + compact (cnt zeroed by memset) ---------
__global__ void k_pre(const float* __restrict__ h, u16* __restrict__ a0,
                      const int* __restrict__ tgt, int* __restrict__ cnt,
                      int* __restrict__ idx1, int* __restrict__ idx2,
                      int* __restrict__ idx3, int* __restrict__ pos,
                      int* __restrict__ tr0, int* __restrict__ tr1,
                      int* __restrict__ tr2, int* __restrict__ tr3){
  const int bid = blockIdx.x, tid = threadIdx.x;
  if (bid < 512){
    int i = (bid * 256 + tid) * 8;
    f32x4 v0 = *(const f32x4*)(h + i);
    f32x4 v1 = *(const f32x4*)(h + i + 4);
    u16x8 o;
    o[0]=f2bf(v0.x); o[1]=f2bf(v0.y); o[2]=f2bf(v0.z); o[3]=f2bf(v0.w);
    o[4]=f2bf(v1.x); o[5]=f2bf(v1.y); o[6]=f2bf(v1.z); o[7]=f2bf(v1.w);
    *(u16x8*)(a0 + i) = o;
  } else {
    int n = (bid - 512) * 256 + tid;
    int tv = tgt[n];
    int p = 0;
    tr0[n] = (tv < 20000) ? tv : -1;
    if (tv >= 20000){
      int b = (tv < 60000) ? 0 : (tv < 180000 ? 1 : 2);
      p = atomicAdd(&cnt[b], 1);
      if (b == 0){ idx1[p] = n; tr1[p] = tv - 20000; }
      else if (b == 1){ idx2[p] = n; tr2[p] = tv - 60000; }
      else { idx3[p] = n; tr3[p] = tv - 180000; }
    }
    pos[n] = p;
  }
}

// ---------------- stage1: pure multi-job transpose ----------------
__global__ void k_stage1(TJobs jobs){
  __shared__ float t[64][65];
  transpose_tile<256>(jobs, blockIdx.x, t, threadIdx.x);
}

// ---------------- proj GEMM body (512 thr): A0 x BTp[400][1024]^T ----------
__device__ __forceinline__
void proj_body(const u16* __restrict__ A, const u16* __restrict__ BT,
               const float* __restrict__ bc,
               u16* __restrict__ A1, u16* __restrict__ A2,
               u16* __restrict__ A3, float* __restrict__ cl,
               int pm, int pn, u16* As, u16* Bs)
{
  constexpr int BK = 64, K = 1024;
  const int tid  = threadIdx.x;
  const int lane = tid & 63, wid = tid >> 6;
  const int wm = wid & 3, wn = wid >> 2;
  const int l15 = lane & 15, l4 = lane >> 4;
  const int m0 = pm * 256;
  const int n0 = pn * 128;

  f32x4 acc[4][4];
  #pragma unroll
  for (int m = 0; m < 4; ++m)
    #pragma unroll
    for (int n = 0; n < 4; ++n){ acc[m][n].x=0.f; acc[m][n].y=0.f; acc[m][n].z=0.f; acc[m][n].w=0.f; }

  for (int kt = 0; kt < K / BK; ++kt){
    #pragma unroll
    for (int i = 0; i < 4; ++i){
      int c = wid * 4 + i;
      int row = c * 8 + lane / 8, kb = lane % 8;
      glds16((const char*)(A + (size_t)(m0 + row) * K + kt * BK) + kb * 16,
             (char*)As + c * 1024);
    }
    #pragma unroll
    for (int i = 0; i < 2; ++i){
      int c = wid * 2 + i;
      int row = c * 8 + lane / 8, kb = lane % 8;
      glds16((const char*)(BT + (size_t)(n0 + row) * K + kt * BK) + kb * 16,
             (char*)Bs + c * 1024);
    }
    __syncthreads();
    #pragma unroll
    for (int ks = 0; ks < 2; ++ks){
      bf16x8 af[4], bfr[4];
      #pragma unroll
      for (int m = 0; m < 4; ++m)
        af[m] = *(const bf16x8*)((const char*)As + (wm*64 + m*16 + l15) * (BK*2) + ks*64 + l4*16);
      #pragma unroll
      for (int n = 0; n < 4; ++n)
        bfr[n] = *(const bf16x8*)((const char*)Bs + (wn*64 + n*16 + l15) * (BK*2) + ks*64 + l4*16);
      #pragma unroll
      for (int m = 0; m < 4; ++m)
        #pragma unroll
        for (int n = 0; n < 4; ++n)
          acc[m][n] = __builtin_amdgcn_mfma_f32_16x16x32_bf16(af[m], bfr[n], acc[m][n], 0, 0, 0);
    }
    __syncthreads();
  }
  #pragma unroll
  for (int m = 0; m < 4; ++m)
    #pragma unroll
    for (int n = 0; n < 4; ++n)
      #pragma unroll
      for (int q = 0; q < 4; ++q){
        int c = n0 + wn*64 + n*16 + l15;
        int r = m0 + wm*64 + m*16 + l4*4 + q;
        float v = acc[m][n][q];
        if (c < 256)      A1[(size_t)r*256 + c] = f2bf(v);
        else if (c < 320) A2[(size_t)r*64 + (c-256)] = f2bf(v);
        else if (c < 336){ u16* p = A3 + (size_t)r*32 + (c-320);
                           p[0] = f2bf(v); p[16] = 0; }
        else if (c < 339) cl[(size_t)r*3 + (c-336)] = v + bc[c-336];
      }
}

// ---------------- proj GEMM + head-BT tail filler (one launch) -------------
__global__ __launch_bounds__(512)
void k_proj_plus(const u16* __restrict__ A, const u16* __restrict__ BT,
                 const float* __restrict__ bc,
                 u16* __restrict__ A1, u16* __restrict__ A2,
                 u16* __restrict__ A3, float* __restrict__ cl, TJobs fill)
{
  __shared__ __align__(16) char smem[49152];
  const int bid = blockIdx.x;
  if (bid < 12){
    proj_body(A, BT, bc, A1, A2, A3, cl, bid / 3, bid % 3,
              (u16*)smem, (u16*)(smem + 32768));
  } else {
    float (*t)[65] = (float(*)[65])smem;
    transpose_tile<512>(fill, bid - 12, t, threadIdx.x);
  }
}

// ---------------- BM=256 GEMM body (R13-proven), blocked B ----------------
__device__ __forceinline__
void gemm256_body(const u16* __restrict__ A, const u16* __restrict__ BT,
                  const float* __restrict__ bias, int K, int N,
                  float* __restrict__ P, int ntiles, int cb, int rb,
                  const int* __restrict__ tgt_rel, float* __restrict__ tl,
                  u16* As, u16* Bs, float* reds, int* trel_s)
{
  constexpr int BK = 64;
  const int tid  = threadIdx.x;
  const int lane = tid & 63, wid = tid >> 6;
  const int wm = wid & 3, wn = wid >> 2;
  const int l15 = lane & 15, l4 = lane >> 4;
  const int m0 = rb * 256;
  const int n0 = cb * 128;
  const int srow = lane >> 3, skb = lane & 7;

  if (tid < 256) trel_s[tid] = tgt_rel[m0 + tid];

  f32x4 acc[4][4];
  #pragma unroll
  for (int m = 0; m < 4; ++m)
    #pragma unroll
    for (int n = 0; n < 4; ++n){ acc[m][n].x=0.f; acc[m][n].y=0.f; acc[m][n].z=0.f; acc[m][n].w=0.f; }

  const int ksteps = K / BK;
  for (int kt = 0; kt < ksteps; ++kt){
    #pragma unroll
    for (int i = 0; i < 4; ++i){
      int c = wid * 4 + i;
      int row = c * 8 + srow;
      int kbs = skb ^ (row & 7);
      glds16((const char*)(A + (size_t)(m0 + row) * K + kt * BK) + kbs * 16,
             (char*)As + c * 1024);
    }
    #pragma unroll
    for (int i = 0; i < 2; ++i){
      int c = wid * 2 + i;
      int row = c * 8 + srow;
      int kbs = skb ^ (row & 7);
      glds16((const char*)(BT + ((size_t)(cb * ksteps + kt) * 128 + row) * 64) + kbs * 16,
             (char*)Bs + c * 1024);
    }
    __syncthreads();
    #pragma unroll
    for (int ks = 0; ks < 2; ++ks){
      bf16x8 af[4], bfr[4];
      #pragma unroll
      for (int m = 0; m < 4; ++m){
        int r = wm*64 + m*16 + l15;
        af[m] = *(const bf16x8*)((const char*)As + r*128 + (((ks*4 + l4) ^ (r & 7)) * 16));
      }
      #pragma unroll
      for (int n = 0; n < 4; ++n){
        int r = wn*64 + n*16 + l15;
        bfr[n] = *(const bf16x8*)((const char*)Bs + r*128 + (((ks*4 + l4) ^ (r & 7)) * 16));
      }
      #pragma unroll
      for (int m = 0; m < 4; ++m)
        #pragma unroll
        for (int n = 0; n < 4; ++n)
          acc[m][n] = __builtin_amdgcn_mfma_f32_16x16x32_bf16(af[m], bfr[n], acc[m][n], 0, 0, 0);
    }
    __syncthreads();
  }

  float bv[4]; bool val[4];
  #pragma unroll
  for (int n = 0; n < 4; ++n){
    int col = n0 + wn*64 + n*16 + l15;
    val[n] = col < N;
    bv[n] = val[n] ? bias[col] : 0.f;
  }
  #pragma unroll
  for (int m = 0; m < 4; ++m)
    #pragma unroll
    for (int q = 0; q < 4; ++q){
      int lrow = wm*64 + m*16 + l4*4 + q;
      int tr = trel_s[lrow];
      float Sl = 0.f;
      #pragma unroll
      for (int n = 0; n < 4; ++n){
        if (val[n]){
          float lg = acc[m][n][q] + bv[n];
          Sl += __expf(lg);
          int col = n0 + wn*64 + n*16 + l15;
          if (tr == col) tl[m0 + lrow] = lg;
        }
      }
      #pragma unroll
      for (int d = 1; d < 16; d <<= 1) Sl += __shfl_xor(Sl, d);
      if (l15 == 0) reds[wn*256 + lrow] = Sl;
    }
  __syncthreads();
  if (wn == 0 && l15 == 0){
    #pragma unroll
    for (int m = 0; m < 4; ++m)
      #pragma unroll
      for (int q = 0; q < 4; ++q){
        int lrow = wm*64 + m*16 + l4*4 + q;
        P[(size_t)(m0 + lrow) * ntiles + cb] = reds[lrow] + reds[256 + lrow];
      }
  }
}

// ---------------- standalone head GEMM (small-ws path) ----------------
__global__ __launch_bounds__(512)
void k_gemm_lse256(const u16* __restrict__ A, const u16* __restrict__ BT,
                   const float* __restrict__ bias, int K, int N,
                   float* __restrict__ P, int ntiles,
                   const int* __restrict__ tgt_rel, float* __restrict__ tl)
{
  __shared__ u16 As[256 * 64];
  __shared__ u16 Bs[128 * 64];
  __shared__ float reds[2 * 256];
  __shared__ int trel_s[256];
  gemm256_body(A, BT, bias, K, N, P, ntiles, blockIdx.x, blockIdx.y,
               tgt_rel, tl, As, Bs, reds, trel_s);
}

// ---------------- mega: head GEMM (XCD-chunked) + tail transposes ---------
__global__ __launch_bounds__(512)
void k_mega(const u16* __restrict__ A, const u16* __restrict__ BT,
            const float* __restrict__ bias, int ntiles,
            float* __restrict__ P, const int* __restrict__ tgt_rel,
            float* __restrict__ tl, int gb, TJobs tails)
{
  __shared__ __align__(16) char smem[52224];
  const int bid = blockIdx.x;
  if (bid < gb){
    const int q = gb >> 3, r = gb & 7;
    const int xcd = bid & 7, ii = bid >> 3;
    const int swz = (xcd < r ? xcd * (q + 1) : r * (q + 1) + (xcd - r) * q) + ii;
    const int cb = swz >> 2, rb = swz & 3;
    u16* As = (u16*)smem;
    u16* Bs = (u16*)(smem + 32768);
    float* reds = (float*)(smem + 49152);
    int* trel_s = (int*)(smem + 51200);
    gemm256_body(A, BT, bias, 1024, 20000, P, ntiles,
                 cb, rb, tgt_rel, tl, As, Bs, reds, trel_s);
  } else {
    float (*t)[65] = (float(*)[65])smem;
    transpose_tile<512>(tails, bid - gb, t, threadIdx.x);
  }
}

// ---------------- t1: 128x128 blocked-B GEMM, indirect A ------------------
__global__ __launch_bounds__(256)
void k_tail1(const u16* __restrict__ A, const u16* __restrict__ BT,
             const float* __restrict__ bias, int K, int N,
             float* __restrict__ P, int ntiles,
             const int* __restrict__ cnt, int bucket,
             const int* __restrict__ trel, const int* __restrict__ ridx,
             float* __restrict__ tl)
{
  constexpr int BK = 64;
  const int cntv = cnt[bucket];
  const int rb = blockIdx.y, cb = blockIdx.x;
  const int m0 = rb * 128;
  if (m0 >= cntv) return;

  __shared__ u16 As[128 * BK];
  __shared__ u16 Bs[128 * BK];
  __shared__ float reds[2 * 128];
  __shared__ int trel_s[128];

  const int tid  = threadIdx.x;
  const int lane = tid & 63, wid = tid >> 6;
  const int wm = wid & 1, wn = wid >> 1;
  const int l15 = lane & 15, l4 = lane >> 4;
  const int n0 = cb * 128;
  const int srow = lane >> 3, skb = lane & 7;

  if (tid < 128) trel_s[tid] = trel[m0 + tid];

  f32x4 acc[4][4];
  #pragma unroll
  for (int m = 0; m < 4; ++m)
    #pragma unroll
    for (int n = 0; n < 4; ++n){ acc[m][n].x=0.f; acc[m][n].y=0.f; acc[m][n].z=0.f; acc[m][n].w=0.f; }

  const int ksteps = K / BK;
  for (int kt = 0; kt < ksteps; ++kt){
    #pragma unroll
    for (int i = 0; i < 4; ++i){
      int c = wid * 4 + i;
      int row = c * 8 + srow;
      int grow = (m0 + row < cntv) ? ridx[m0 + row] : ridx[0];
      int kbs = skb ^ (row & 7);
      glds16((const char*)(A + (size_t)grow * K + kt * BK) + kbs * 16,
             (char*)As + c * 1024);
    }
    #pragma unroll
    for (int i = 0; i < 4; ++i){
      int c = wid * 4 + i;
      int row = c * 8 + srow;
      int kbs = skb ^ (row & 7);
      glds16((const char*)(BT + ((size_t)(cb * ksteps + kt) * 128 + row) * 64) + kbs * 16,
             (char*)Bs + c * 1024);
    }
    __syncthreads();
    #pragma unroll
    for (int ks = 0; ks < 2; ++ks){
      bf16x8 af[4], bfr[4];
      #pragma unroll
      for (int m = 0; m < 4; ++m){
        int r = wm*64 + m*16 + l15;
        af[m] = *(const bf16x8*)((const char*)As + r*128 + (((ks*4 + l4) ^ (r & 7)) * 16));
      }
      #pragma unroll
      for (int n = 0; n < 4; ++n){
        int r = wn*64 + n*16 + l15;
        bfr[n] = *(const bf16x8*)((const char*)Bs + r*128 + (((ks*4 + l4) ^ (r & 7)) * 16));
      }
      #pragma unroll
      for (int m = 0; m < 4; ++m)
        #pragma unroll
        for (int n = 0; n < 4; ++n)
          acc[m][n] = __builtin_amdgcn_mfma_f32_16x16x32_bf16(af[m], bfr[n], acc[m][n], 0, 0, 0);
    }
    __syncthreads();
  }

  float bv[4]; bool val[4];
  #pragma unroll
  for (int n = 0; n < 4; ++n){
    int col = n0 + wn*64 + n*16 + l15;
    val[n] = col < N;
    bv[n] = val[n] ? bias[col] : 0.f;
  }
  #pragma unroll
  for (int m = 0; m < 4; ++m)
    #pragma unroll
    for (int q = 0; q < 4; ++q){
      int lrow = wm*64 + m*16 + l4*4 + q;
      int tr = trel_s[lrow];
      bool live = (m0 + lrow) < cntv;
      float Sl = 0.f;
      #pragma unroll
      for (int n = 0; n < 4; ++n){
        if (val[n]){
          float lg = acc[m][n][q] + bv[n];
          Sl += __expf(lg);
          int col = n0 + wn*64 + n*16 + l15;
          if (live && tr == col) tl[ridx[m0 + lrow]] = lg;
        }
      }
      #pragma unroll
      for (int d = 1; d < 16; d <<= 1) Sl += __shfl_xor(Sl, d);
      if (l15 == 0) reds[wn*128 + lrow] = Sl;
    }
  __syncthreads();
  if (wn == 0 && l15 == 0){
    #pragma unroll
    for (int m = 0; m < 4; ++m)
      #pragma unroll
      for (int q = 0; q < 4; ++q){
        int lrow = wm*64 + m*16 + l4*4 + q;
        P[(size_t)(m0 + lrow) * ntiles + cb] = reds[lrow] + reds[128 + lrow];
      }
  }
}

// ---------------- t2/t3: B-streaming GEMM, indirect A ---------------------
template<int NC, int BK>
__global__ __launch_bounds__(256)
void k_tail_s(const u16* __restrict__ A, const u16* __restrict__ BT,
              const float* __restrict__ bias, int N,
              float* __restrict__ P, int ntiles,
              const int* __restrict__ cnt, int bucket,
              const int* __restrict__ trel, const int* __restrict__ ridx,
              float* __restrict__ tl)
{
  constexpr int CH  = BK / 8;
  constexpr int LPR = CH;
  constexpr int RPC = 64 / LPR;
  constexpr int CPW = (128 * BK * 2 / 1024) / 4;
  const int cntv = cnt[bucket];
  const int yb = blockIdx.y, cg = blockIdx.x;
  const int m0 = yb * 128;
  if (m0 >= cntv) return;

  __shared__ u16 As[128 * BK];
  __shared__ u16 BsM[2][128 * BK];
  __shared__ float reds[2 * 128];
  __shared__ int trel_s[128];

  const int tid  = threadIdx.x;
  const int lane = tid & 63, wid = tid >> 6;
  const int wm = wid & 1, wn = wid >> 1;
  const int l15 = lane & 15, l4 = lane >> 4;
  const int srow = lane / LPR, skb = lane % LPR;

  if (tid < 128) trel_s[tid] = trel[m0 + tid];

  #pragma unroll
  for (int i = 0; i < CPW; ++i){
    int c = wid * CPW + i;
    int row = c * RPC + srow;
    int grow = (m0 + row < cntv) ? ridx[m0 + row] : ridx[0];
    int kbs = skb ^ (row & (CH - 1));
    glds16((const char*)(A + (size_t)grow * BK) + kbs * 16,
           (char*)As + c * 1024);
  }
  {
    int ci0 = cg * NC;
    if (ci0 < ntiles){
      #pragma unroll
      for (int i = 0; i < CPW; ++i){
        int c = wid * CPW + i;
        int row = c * RPC + srow;
        int kbs = skb ^ (row & (CH - 1));
        glds16((const char*)(BT + (size_t)(ci0*128 + row) * BK) + kbs * 16,
               (char*)BsM[0] + c * 1024);
      }
    }
  }
  __syncthreads();

  int buf = 0;
  for (int ct = 0; ct < NC; ++ct){
    int ci = cg * NC + ct;
    if (ci >= ntiles) break;
    if (ct + 1 < NC && ci + 1 < ntiles){
      #pragma unroll
      for (int i = 0; i < CPW; ++i){
        int c = wid * CPW + i;
        int row = c * RPC + srow;
        int kbs = skb ^ (row & (CH - 1));
        glds16((const char*)(BT + (size_t)((ci+1)*128 + row) * BK) + kbs * 16,
               (char*)BsM[buf ^ 1] + c * 1024);
      }
    }
    f32x4 acc[4][4];
    #pragma unroll
    for (int m = 0; m < 4; ++m)
      #pragma unroll
      for (int n = 0; n < 4; ++n){ acc[m][n].x=0.f; acc[m][n].y=0.f; acc[m][n].z=0.f; acc[m][n].w=0.f; }
    #pragma unroll
    for (int ks = 0; ks < BK / 32; ++ks){
      bf16x8 af[4], bfr[4];
      #pragma unroll
      for (int m = 0; m < 4; ++m){
        int r = wm*64 + m*16 + l15;
        af[m] = *(const bf16x8*)((const char*)As + r*(BK*2) + (((ks*4 + l4) ^ (r & (CH-1))) * 16));
      }
      #pragma unroll
      for (int n = 0; n < 4; ++n){
        int r = wn*64 + n*16 + l15;
        bfr[n] = *(const bf16x8*)((const char*)BsM[buf] + r*(BK*2) + (((ks*4 + l4) ^ (r & (CH-1))) * 16));
      }
      #pragma unroll
      for (int m = 0; m < 4; ++m)
        #pragma unroll
        for (int n = 0; n < 4; ++n)
          acc[m][n] = __builtin_amdgcn_mfma_f32_16x16x32_bf16(af[m], bfr[n], acc[m][n], 0, 0, 0);
    }
    const int n0 = ci * 128;
    float bv[4]; bool val[4];
    #pragma unroll
    for (int n = 0; n < 4; ++n){
      int col = n0 + wn*64 + n*16 + l15;
      val[n] = col < N;
      bv[n] = val[n] ? bias[col] : 0.f;
    }
    #pragma unroll
    for (int m = 0; m < 4; ++m)
      #pragma unroll
      for (int q = 0; q < 4; ++q){
        int lrow = wm*64 + m*16 + l4*4 + q;
        int tr = trel_s[lrow];
        bool live = (m0 + lrow) < cntv;
        float Sl = 0.f;
        #pragma unroll
        for (int n = 0; n < 4; ++n){
          if (val[n]){
            float lg = acc[m][n][q] + bv[n];
            Sl += __expf(lg);
            int col = n0 + wn*64 + n*16 + l15;
            if (live && tr == col) tl[ridx[m0 + lrow]] = lg;
          }
        }
        #pragma unroll
        for (int d = 1; d < 16; d <<= 1) Sl += __shfl_xor(Sl, d);
        if (l15 == 0) reds[wn*128 + lrow] = Sl;
      }
    __syncthreads();
    if (wn == 0 && l15 == 0){
      #pragma unroll
      for (int m = 0; m < 4; ++m)
        #pragma unroll
        for (int q = 0; q < 4; ++q){
          int lrow = wm*64 + m*16 + l4*4 + q;
          P[(size_t)(m0 + lrow) * ntiles + ci] = reds[lrow] + reds[128 + lrow];
        }
    }
    __syncthreads();
    buf ^= 1;
  }
}

// ---------------- final combine (P = f32 partial sums of exp) ----------------
__global__ void k_finalize(const int* __restrict__ tgt, const float* __restrict__ P,
                           const float* __restrict__ cl, const float* __restrict__ tl,
                           const int* __restrict__ pos, float* __restrict__ out)
{
  const int NT0 = 157, NT1 = 313, NT2 = 938, NT3 = 686;
  int n = blockIdx.x * 4 + (threadIdx.x >> 6);
  int lane = threadIdx.x & 63;
  int t = tgt[n];

  float s = 0.f;
  const float* p0 = P + (size_t)n * NT0;
  for (int i = lane; i < NT0; i += 64) s += p0[i];
  if (lane < 3) s += __expf(cl[n*3 + lane]);
  #pragma unroll
  for (int d = 1; d < 64; d <<= 1) s += __shfl_xor(s, d);
  float lse_head = logf(s);

  float nll;
  if (t < 20000){
    nll = lse_head - tl[n];
  } else {
    int seg, nt; size_t base;
    if      (t <  60000){ seg = 1; nt = NT1; base = (size_t)1024 * NT0; }
    else if (t < 180000){ seg = 2; nt = NT2; base = (size_t)1024 * (NT0 + NT1); }
    else                { seg = 3; nt = NT3; base = (size_t)1024 * (NT0 + NT1 + NT2); }
    float s2 = 0.f;
    const float* ps = P + base + (size_t)pos[n] * nt;
    for (int i = lane; i < nt; i += 64) s2 += ps[i];
    #pragma unroll
    for (int d = 1; d < 64; d <<= 1) s2 += __shfl_xor(s2, d);
    float lse_t = logf(s2);
    // reference quirk: bucket i uses head_lp[:, -i] == cluster logit index 3-i
    nll = lse_head - cl[n*3 + (3 - seg)] + lse_t - tl[n];
  }
  if (lane == 0) out[n] = nll;
}

// ---------------------------------------------------------------------------
extern "C" void kernel_launch(void* const* d_in, const int* in_sizes, int n_in,
                              void* d_out, int out_size, void* d_ws, size_t ws_size,
                              hipStream_t stream)
{
  const float* hidden = (const float*)d_in[0];
  const int*   target = (const int*)d_in[1];
  const float* W_head = (const float*)d_in[2];
  const float* b_head = (const float*)d_in[3];
  const float* W_clu  = (const float*)d_in[4];
  const float* b_clu  = (const float*)d_in[5];
  const float* W_p1   = (const float*)d_in[6];
  const float* W_t1   = (const float*)d_in[7];
  const float* b_t1   = (const float*)d_in[8];
  const float* W_p2   = (const float*)d_in[9];
  const float* W_t2   = (const float*)d_in[10];
  const float* b_t2   = (const float*)d_in[11];
  const float* W_p3   = (const float*)d_in[12];
  const float* W_t3   = (const float*)d_in[13];
  const float* b_t3   = (const float*)d_in[14];
  float* out = (float*)d_out;

  char* ws = (char*)d_ws;
  u16*   A0  = (u16*)(ws + 0);          // [1024][1024] bf16
  u16*   A1  = (u16*)(ws + 2097152);    // [1024][256]
  u16*   A2  = (u16*)(ws + 2621440);    // [1024][64]
  u16*   A3  = (u16*)(ws + 2752512);    // [1024][32]
  float* cl  = (float*)(ws + 2883584);  // [1024][3]
  float* tl  = (float*)(ws + 2895872);  // [1024]
  float* P   = (float*)(ws + 2899968);  // [1024][2094] f32 (8.6MB)
  u16*   BTpOv = (u16*)(ws + 2899968);  // small-ws proj overlay (sequential)
  u16*   BTh = (u16*)(ws + 11476992);   // head BT blocked [157][16][128][64]
  int*   cnt  = (int*)(ws + 52633600);
  int*   idx1 = (int*)(ws + 52633856);
  int*   idx2 = (int*)(ws + 52637952);
  int*   idx3 = (int*)(ws + 52642048);
  int*   pos  = (int*)(ws + 52646144);
  int*   trel = (int*)(ws + 52650240);  // [4096]: tr0|tr1|tr2|tr3
  int*   tr0 = trel, *tr1 = trel + 1024, *tr2 = trel + 2048, *tr3 = trel + 3072;
  u16*   BT1  = (u16*)(ws + 52666624);  // t1 blocked [313][4][128][64] (20.5MB)
  u16*   BT2  = (u16*)(ws + 73179392);  // [120064][64]  (15.4 MB)
  u16*   BT3  = (u16*)(ws + 88547584);  // [87808][32]   ( 5.6 MB)
  u16*   BTpD = (u16*)(ws + 94167296);  // dedicated proj BT [400][1024] (0.8MB)
  const size_t needA = 94986496;
  const bool bigws = ws_size >= needA;
  u16* BTp = bigws ? BTpD : BTpOv;

  float* P0  = P;
  float* Pp1 = P + (size_t)1024 * 157;
  float* Pp2 = P + (size_t)1024 * (157 + 313);
  float* Pp3 = P + (size_t)1024 * (157 + 313 + 938);

  auto addj = [](TJobs& tj, int& nb, const float* W, u16* B, int K, int N,
                 int ldw, int Kpad, int nrows, int blk){
    int nx = (nrows + 63) / 64;
    int ny = (Kpad + 63) / 64;
    tj.j[tj.nj++] = TJob{W, B, K, N, ldw, Kpad, nrows, nx, nb, blk};
    nb += nx * ny;
  };

  hipMemsetAsync(cnt, 0, 16, stream);
  k_pre<<<516, 256, 0, stream>>>(hidden, A0, target, cnt,
                                 idx1, idx2, idx3, pos, tr0, tr1, tr2, tr3);

  if (bigws){
    // ---- stage1: proj transposes + head-BT panels 0..132 ----
    TJobs tj{}; int nb = 0;
    addj(tj, nb, W_p1, BTp, 1024, 256, 256, 1024, 256, 0);
    addj(tj, nb, W_p2, BTp + (size_t)256*1024, 1024, 64, 64, 1024, 64, 0);
    addj(tj, nb, W_p3, BTp + (size_t)320*1024, 1024, 16, 16, 1024, 16, 0);
    addj(tj, nb, W_clu, BTp + (size_t)336*1024, 1024, 3, 3, 1024, 64, 0);
    addj(tj, nb, W_head, BTh, 1024, 20000, 20000, 1024, 17024, 1);
    k_stage1<<<nb, 256, 0, stream>>>(tj);

    // ---- proj GEMM + head-BT tail (panels 133..156) as filler ----
    TJobs fj{}; int nf = 0;
    addj(fj, nf, W_head + 17024, BTh + (size_t)133*131072, 1024,
         20000 - 17024 /*=2976*/, 20000, 1024, 20096 - 17024 /*=3072*/, 1);
    k_proj_plus<<<12 + nf, 512, 0, stream>>>(A0, BTp, b_clu, A1, A2, A3, cl, fj);

    // ---- mega: head GEMM (628 first, XCD-chunked) + tail transposes ----
    TJobs tt{}; int nbT = 0;
    addj(tt, nbT, W_t1, BT1, 256, 40000, 40000, 256, 40064, 1);
    addj(tt, nbT, W_t2, BT2, 64, 120000, 120000, 64, 120064, 0);
    addj(tt, nbT, W_t3, BT3, 16, 87735, 87735, 32, 87808, 0);
    const int gb = 157 * 4;
    k_mega<<<gb + nbT, 512, 0, stream>>>(A0, BTh, b_head, 157, P0, tr0, tl, gb, tt);

    // ---- tail GEMMs: separate launches (per-kernel regalloc) ----
    k_tail1<<<dim3(313, 8), 256, 0, stream>>>(A1, BT1, b_t1, 256, 40000,
        Pp1, 313, cnt, 0, tr1, idx1, tl);
    k_tail_s<4, 64><<<dim3(235, 8), 256, 0, stream>>>(A2, BT2, b_t2, 120000,
        Pp2, 938, cnt, 1, tr2, idx2, tl);
    k_tail_s<4, 32><<<dim3(172, 8), 256, 0, stream>>>(A3, BT3, b_t3, 87735,
        Pp3, 686, cnt, 2, tr3, idx3, tl);
  } else {
    // small ws: sequential, tails reuse BTh region
    TJobs tj{}; int nb = 0;
    addj(tj, nb, W_p1, BTp, 1024, 256, 256, 1024, 256, 0);
    addj(tj, nb, W_p2, BTp + (size_t)256*1024, 1024, 64, 64, 1024, 64, 0);
    addj(tj, nb, W_p3, BTp + (size_t)320*1024, 1024, 16, 16, 1024, 16, 0);
    addj(tj, nb, W_clu, BTp + (size_t)336*1024, 1024, 3, 3, 1024, 64, 0);
    addj(tj, nb, W_head, BTh, 1024, 20000, 20000, 1024, 20096, 1);
    k_stage1<<<nb, 256, 0, stream>>>(tj);

    TJobs fj0{};
    k_proj_plus<<<12, 512, 0, stream>>>(A0, BTp, b_clu, A1, A2, A3, cl, fj0);

    k_gemm_lse256<<<dim3(157, 4), 512, 0, stream>>>(A0, BTh, b_head, 1024, 20000,
        P0, 157, tr0, tl);

    TJobs s1{}; int n1 = 0;
    addj(s1, n1, W_t1, BTh, 256, 40000, 40000, 256, 40064, 1);
    k_stage1<<<n1, 256, 0, stream>>>(s1);
    k_tail1<<<dim3(313, 8), 256, 0, stream>>>(A1, BTh, b_t1, 256, 40000,
        Pp1, 313, cnt, 0, tr1, idx1, tl);

    TJobs s2{}; int n2 = 0;
    addj(s2, n2, W_t2, BTh, 64, 120000, 120000, 64, 120064, 0);
    k_stage1<<<n2, 256, 0, stream>>>(s2);
    k_tail_s<4, 64><<<dim3(235, 8), 256, 0, stream>>>(A2, BTh, b_t2, 120000,
        Pp2, 938, cnt, 1, tr2, idx2, tl);

    TJobs s3{}; int n3 = 0;
    addj(s3, n3, W_t3, BTh, 16, 87735, 87735, 32, 87808, 0);
    k_stage1<<<n3, 256, 0, stream>>>(s3);
    k_tail_s<4, 32><<<dim3(172, 8), 256, 0, stream>>>(A3, BTh, b_t3, 87735,
        Pp3, 686, cnt, 2, tr3, idx3, tl);
  }

  k_finalize<<<256, 256, 0, stream>>>(target, P, cl, tl, pos, out);
}

// Round 23
// 252.417 us; speedup vs baseline: 1.0189x; 1.0189x over previous
//
#include <hip/hip_runtime.h>
#include <cstdint>
#include <cstddef>

// ---------------------------------------------------------------------------
// Adaptive log-softmax NLL. bf16 MFMA GEMMs fused with online logsumexp.
// R23: R21 base (256.5us best) + T5 s_setprio(1) around the MFMA cluster in
// gemm256_body. Mechanism: mega co-schedules GEMM waves (MFMA) with
// transpose-filler waves (memory) on the same CUs -- role diversity is T5's
// prerequisite (m191 +4-7%; null only on lockstep m190). Everything else
// identical to R21.
// ---------------------------------------------------------------------------

typedef unsigned short u16;
typedef __attribute__((ext_vector_type(8))) __bf16 bf16x8;
typedef __attribute__((ext_vector_type(8))) u16 u16x8;
typedef __attribute__((ext_vector_type(4))) float f32x4;

#define AS1 __attribute__((address_space(1)))
#define AS3 __attribute__((address_space(3)))

__device__ __forceinline__ u16 f2bf(float f){
  union { float f; unsigned u; } v; v.f = f;
  unsigned r = v.u + 0x7fffu + ((v.u >> 16) & 1u);  // RNE
  return (u16)(r >> 16);
}
__device__ __forceinline__ void glds16(const void* g, void* l){
  __builtin_amdgcn_global_load_lds((AS1 unsigned*)(uintptr_t)g,
                                   (AS3 unsigned*)(unsigned)(uintptr_t)l, 16, 0, 0);
}

// ---------------- init: zero cnt, trel = -1 ----------------
__global__ void k_init(int* __restrict__ cnt, int* __restrict__ trel){
  int i = blockIdx.x * 256 + threadIdx.x;
  trel[i] = -1;
  if (i < 4) cnt[i] = 0;
}

// ---------------- transpose job descriptors ----------------
struct TJob { const float* W; u16* BT; int K, N, Kpad, nrows, nx, base, blk; };
struct TJobs { TJob j[8]; int nj; };

template<int TPB>
__device__ __forceinline__ void transpose_tile(const TJobs& jobs, int id,
                                               float (*t)[65], int tid){
  int ji = 0;
  #pragma unroll
  for (int i = 1; i < 8; ++i)
    if (i < jobs.nj && id >= jobs.j[i].base) ji = i;
  TJob jb = jobs.j[ji];
  int local = id - jb.base;
  int bx = local % jb.nx;
  int by = local / jb.nx;

  const int n0 = bx * 64;
  const int k0 = by * 64;
  const bool al = (jb.N & 3) == 0;
  for (int i = tid; i < 64*16; i += TPB){
    int r = i >> 4, c4 = (i & 15) * 4;
    int k = k0 + r, n = n0 + c4;
    f32x4 v; v.x=0.f; v.y=0.f; v.z=0.f; v.w=0.f;
    if (k < jb.K){
      if (al && n + 3 < jb.N) v = *(const f32x4*)(jb.W + (size_t)k * jb.N + n);
      else { for (int q = 0; q < 4; ++q) if (n + q < jb.N) v[q] = jb.W[(size_t)k * jb.N + n + q]; }
    }
    t[r][c4] = v.x; t[r][c4+1] = v.y; t[r][c4+2] = v.z; t[r][c4+3] = v.w;
  }
  __syncthreads();
  for (int i = tid; i < 64*8; i += TPB){
    int rn = i >> 3, c8 = (i & 7) * 8;
    int n = n0 + rn;
    if (k0 + c8 < jb.Kpad && n < jb.nrows){
      u16x8 o;
      #pragma unroll
      for (int q = 0; q < 8; ++q) o[q] = f2bf(t[c8 + q][rn]);
      size_t off;
      if (jb.blk)
        off = (((size_t)(n >> 7) * (jb.Kpad >> 6) + (k0 >> 6)) * 128 + (n & 127)) * 64 + c8;
      else
        off = (size_t)n * jb.Kpad + k0 + c8;
      *(u16x8*)(jb.BT + off) = o;
    }
  }
}

// ---------------- stage1: transposes + cvt_hidden + compact ----------------
__global__ void k_stage1(TJobs jobs, int nbT, int ncvt,
                         const float* __restrict__ h, u16* __restrict__ a0,
                         const int* __restrict__ tgt, int* __restrict__ cnt,
                         int* __restrict__ idx1, int* __restrict__ idx2,
                         int* __restrict__ idx3, int* __restrict__ pos,
                         int* __restrict__ tr0, int* __restrict__ tr1,
                         int* __restrict__ tr2, int* __restrict__ tr3){
  __shared__ float t[64][65];
  const int bid = blockIdx.x, tid = threadIdx.x;
  if (bid < nbT){
    transpose_tile<256>(jobs, bid, t, tid);
  } else if (bid < nbT + ncvt){
    int i = ((bid - nbT) * 256 + tid) * 8;
    f32x4 v0 = *(const f32x4*)(h + i);
    f32x4 v1 = *(const f32x4*)(h + i + 4);
    u16x8 o;
    o[0]=f2bf(v0.x); o[1]=f2bf(v0.y); o[2]=f2bf(v0.z); o[3]=f2bf(v0.w);
    o[4]=f2bf(v1.x); o[5]=f2bf(v1.y); o[6]=f2bf(v1.z); o[7]=f2bf(v1.w);
    *(u16x8*)(a0 + i) = o;
  } else {
    int n = (bid - nbT - ncvt) * 256 + tid;
    int tv = tgt[n];
    int p = 0;
    tr0[n] = (tv < 20000) ? tv : -1;
    if (tv >= 20000){
      int b = (tv < 60000) ? 0 : (tv < 180000 ? 1 : 2);
      p = atomicAdd(&cnt[b], 1);
      if (b == 0){ idx1[p] = n; tr1[p] = tv - 20000; }
      else if (b == 1){ idx2[p] = n; tr2[p] = tv - 60000; }
      else { idx3[p] = n; tr3[p] = tv - 180000; }
    }
    pos[n] = p;
  }
}

// ---------------- proj GEMM body (512 thr): A0 x BTp[400][1024]^T ----------
__device__ __forceinline__
void proj_body(const u16* __restrict__ A, const u16* __restrict__ BT,
               const float* __restrict__ bc,
               u16* __restrict__ A1, u16* __restrict__ A2,
               u16* __restrict__ A3, float* __restrict__ cl,
               int pm, int pn, u16* As, u16* Bs)
{
  constexpr int BK = 64, K = 1024;
  const int tid  = threadIdx.x;
  const int lane = tid & 63, wid = tid >> 6;
  const int wm = wid & 3, wn = wid >> 2;
  const int l15 = lane & 15, l4 = lane >> 4;
  const int m0 = pm * 256;
  const int n0 = pn * 128;

  f32x4 acc[4][4];
  #pragma unroll
  for (int m = 0; m < 4; ++m)
    #pragma unroll
    for (int n = 0; n < 4; ++n){ acc[m][n].x=0.f; acc[m][n].y=0.f; acc[m][n].z=0.f; acc[m][n].w=0.f; }

  for (int kt = 0; kt < K / BK; ++kt){
    #pragma unroll
    for (int i = 0; i < 4; ++i){
      int c = wid * 4 + i;
      int row = c * 8 + lane / 8, kb = lane % 8;
      glds16((const char*)(A + (size_t)(m0 + row) * K + kt * BK) + kb * 16,
             (char*)As + c * 1024);
    }
    #pragma unroll
    for (int i = 0; i < 2; ++i){
      int c = wid * 2 + i;
      int row = c * 8 + lane / 8, kb = lane % 8;
      glds16((const char*)(BT + (size_t)(n0 + row) * K + kt * BK) + kb * 16,
             (char*)Bs + c * 1024);
    }
    __syncthreads();
    #pragma unroll
    for (int ks = 0; ks < 2; ++ks){
      bf16x8 af[4], bfr[4];
      #pragma unroll
      for (int m = 0; m < 4; ++m)
        af[m] = *(const bf16x8*)((const char*)As + (wm*64 + m*16 + l15) * (BK*2) + ks*64 + l4*16);
      #pragma unroll
      for (int n = 0; n < 4; ++n)
        bfr[n] = *(const bf16x8*)((const char*)Bs + (wn*64 + n*16 + l15) * (BK*2) + ks*64 + l4*16);
      #pragma unroll
      for (int m = 0; m < 4; ++m)
        #pragma unroll
        for (int n = 0; n < 4; ++n)
          acc[m][n] = __builtin_amdgcn_mfma_f32_16x16x32_bf16(af[m], bfr[n], acc[m][n], 0, 0, 0);
    }
    __syncthreads();
  }
  #pragma unroll
  for (int m = 0; m < 4; ++m)
    #pragma unroll
    for (int n = 0; n < 4; ++n)
      #pragma unroll
      for (int q = 0; q < 4; ++q){
        int c = n0 + wn*64 + n*16 + l15;
        int r = m0 + wm*64 + m*16 + l4*4 + q;
        float v = acc[m][n][q];
        if (c < 256)      A1[(size_t)r*256 + c] = f2bf(v);
        else if (c < 320) A2[(size_t)r*64 + (c-256)] = f2bf(v);
        else if (c < 336){ u16* p = A3 + (size_t)r*32 + (c-320);
                           p[0] = f2bf(v); p[16] = 0; }
        else if (c < 339) cl[(size_t)r*3 + (c-336)] = v + bc[c-336];
      }
}

// ---------------- BM=256 GEMM body (R13-proven), blocked B, T5 setprio -----
__device__ __forceinline__
void gemm256_body(const u16* __restrict__ A, const u16* __restrict__ BT,
                  const float* __restrict__ bias, int K, int N,
                  float* __restrict__ P, int ntiles, int cb, int rb,
                  const int* __restrict__ tgt_rel, float* __restrict__ tl,
                  u16* As, u16* Bs, float* reds, int* trel_s)
{
  constexpr int BK = 64;
  const int tid  = threadIdx.x;
  const int lane = tid & 63, wid = tid >> 6;
  const int wm = wid & 3, wn = wid >> 2;
  const int l15 = lane & 15, l4 = lane >> 4;
  const int m0 = rb * 256;
  const int n0 = cb * 128;
  const int srow = lane >> 3, skb = lane & 7;

  if (tid < 256) trel_s[tid] = tgt_rel[m0 + tid];

  f32x4 acc[4][4];
  #pragma unroll
  for (int m = 0; m < 4; ++m)
    #pragma unroll
    for (int n = 0; n < 4; ++n){ acc[m][n].x=0.f; acc[m][n].y=0.f; acc[m][n].z=0.f; acc[m][n].w=0.f; }

  const int ksteps = K / BK;
  for (int kt = 0; kt < ksteps; ++kt){
    #pragma unroll
    for (int i = 0; i < 4; ++i){
      int c = wid * 4 + i;
      int row = c * 8 + srow;
      int kbs = skb ^ (row & 7);
      glds16((const char*)(A + (size_t)(m0 + row) * K + kt * BK) + kbs * 16,
             (char*)As + c * 1024);
    }
    #pragma unroll
    for (int i = 0; i < 2; ++i){
      int c = wid * 2 + i;
      int row = c * 8 + srow;
      int kbs = skb ^ (row & 7);
      glds16((const char*)(BT + ((size_t)(cb * ksteps + kt) * 128 + row) * 64) + kbs * 16,
             (char*)Bs + c * 1024);
    }
    __syncthreads();
    __builtin_amdgcn_s_setprio(1);     // T5: prioritize MFMA waves over
    #pragma unroll                     // co-resident transpose-filler waves
    for (int ks = 0; ks < 2; ++ks){
      bf16x8 af[4], bfr[4];
      #pragma unroll
      for (int m = 0; m < 4; ++m){
        int r = wm*64 + m*16 + l15;
        af[m] = *(const bf16x8*)((const char*)As + r*128 + (((ks*4 + l4) ^ (r & 7)) * 16));
      }
      #pragma unroll
      for (int n = 0; n < 4; ++n){
        int r = wn*64 + n*16 + l15;
        bfr[n] = *(const bf16x8*)((const char*)Bs + r*128 + (((ks*4 + l4) ^ (r & 7)) * 16));
      }
      #pragma unroll
      for (int m = 0; m < 4; ++m)
        #pragma unroll
        for (int n = 0; n < 4; ++n)
          acc[m][n] = __builtin_amdgcn_mfma_f32_16x16x32_bf16(af[m], bfr[n], acc[m][n], 0, 0, 0);
    }
    __builtin_amdgcn_s_setprio(0);
    __syncthreads();
  }

  float bv[4]; bool val[4];
  #pragma unroll
  for (int n = 0; n < 4; ++n){
    int col = n0 + wn*64 + n*16 + l15;
    val[n] = col < N;
    bv[n] = val[n] ? bias[col] : 0.f;
  }
  #pragma unroll
  for (int m = 0; m < 4; ++m)
    #pragma unroll
    for (int q = 0; q < 4; ++q){
      int lrow = wm*64 + m*16 + l4*4 + q;
      int tr = trel_s[lrow];
      float Sl = 0.f;
      #pragma unroll
      for (int n = 0; n < 4; ++n){
        if (val[n]){
          float lg = acc[m][n][q] + bv[n];
          Sl += __expf(lg);
          int col = n0 + wn*64 + n*16 + l15;
          if (tr == col) tl[m0 + lrow] = lg;
        }
      }
      #pragma unroll
      for (int d = 1; d < 16; d <<= 1) Sl += __shfl_xor(Sl, d);
      if (l15 == 0) reds[wn*256 + lrow] = Sl;
    }
  __syncthreads();
  if (wn == 0 && l15 == 0){
    #pragma unroll
    for (int m = 0; m < 4; ++m)
      #pragma unroll
      for (int q = 0; q < 4; ++q){
        int lrow = wm*64 + m*16 + l4*4 + q;
        P[(size_t)(m0 + lrow) * ntiles + cb] = reds[lrow] + reds[256 + lrow];
      }
  }
}

// ---------------- standalone head GEMM (small-ws path) ----------------
__global__ __launch_bounds__(512)
void k_gemm_lse256(const u16* __restrict__ A, const u16* __restrict__ BT,
                   const float* __restrict__ bias, int K, int N,
                   float* __restrict__ P, int ntiles,
                   const int* __restrict__ tgt_rel, float* __restrict__ tl)
{
  __shared__ u16 As[256 * 64];
  __shared__ u16 Bs[128 * 64];
  __shared__ float reds[2 * 256];
  __shared__ int trel_s[256];
  gemm256_body(A, BT, bias, K, N, P, ntiles, blockIdx.x, blockIdx.y,
               tgt_rel, tl, As, Bs, reds, trel_s);
}

// ---------------- standalone proj GEMM ----------------
__global__ __launch_bounds__(512)
void k_proj_gemm(const u16* __restrict__ A, const u16* __restrict__ BT,
                 const float* __restrict__ bc,
                 u16* __restrict__ A1, u16* __restrict__ A2,
                 u16* __restrict__ A3, float* __restrict__ cl)
{
  __shared__ u16 As[256 * 64];
  __shared__ u16 Bs[128 * 64];
  proj_body(A, BT, bc, A1, A2, A3, cl, blockIdx.y, blockIdx.x, As, Bs);
}

// ---------------- mega: head GEMM (XCD-chunked) + tail transposes ---------
__global__ __launch_bounds__(512)
void k_mega(const u16* __restrict__ A, const u16* __restrict__ BT,
            const float* __restrict__ bias, int ntiles,
            float* __restrict__ P, const int* __restrict__ tgt_rel,
            float* __restrict__ tl, int gb, TJobs tails)
{
  __shared__ __align__(16) char smem[52224];
  const int bid = blockIdx.x;
  if (bid < gb){
    const int q = gb >> 3, r = gb & 7;
    const int xcd = bid & 7, ii = bid >> 3;
    const int swz = (xcd < r ? xcd * (q + 1) : r * (q + 1) + (xcd - r) * q) + ii;
    const int cb = swz >> 2, rb = swz & 3;
    u16* As = (u16*)smem;
    u16* Bs = (u16*)(smem + 32768);
    float* reds = (float*)(smem + 49152);
    int* trel_s = (int*)(smem + 51200);
    gemm256_body(A, BT, bias, 1024, 20000, P, ntiles,
                 cb, rb, tgt_rel, tl, As, Bs, reds, trel_s);
  } else {
    float (*t)[65] = (float(*)[65])smem;
    transpose_tile<512>(tails, bid - gb, t, threadIdx.x);
  }
}

// ---------------- t1: 128x128 blocked-B GEMM, indirect A ------------------
__global__ __launch_bounds__(256)
void k_tail1(const u16* __restrict__ A, const u16* __restrict__ BT,
             const float* __restrict__ bias, int K, int N,
             float* __restrict__ P, int ntiles,
             const int* __restrict__ cnt, int bucket,
             const int* __restrict__ trel, const int* __restrict__ ridx,
             float* __restrict__ tl)
{
  constexpr int BK = 64;
  const int cntv = cnt[bucket];
  const int rb = blockIdx.y, cb = blockIdx.x;
  const int m0 = rb * 128;
  if (m0 >= cntv) return;

  __shared__ u16 As[128 * BK];
  __shared__ u16 Bs[128 * BK];
  __shared__ float reds[2 * 128];
  __shared__ int trel_s[128];

  const int tid  = threadIdx.x;
  const int lane = tid & 63, wid = tid >> 6;
  const int wm = wid & 1, wn = wid >> 1;
  const int l15 = lane & 15, l4 = lane >> 4;
  const int n0 = cb * 128;
  const int srow = lane >> 3, skb = lane & 7;

  if (tid < 128) trel_s[tid] = trel[m0 + tid];

  f32x4 acc[4][4];
  #pragma unroll
  for (int m = 0; m < 4; ++m)
    #pragma unroll
    for (int n = 0; n < 4; ++n){ acc[m][n].x=0.f; acc[m][n].y=0.f; acc[m][n].z=0.f; acc[m][n].w=0.f; }

  const int ksteps = K / BK;
  for (int kt = 0; kt < ksteps; ++kt){
    #pragma unroll
    for (int i = 0; i < 4; ++i){
      int c = wid * 4 + i;
      int row = c * 8 + srow;
      int grow = (m0 + row < cntv) ? ridx[m0 + row] : ridx[0];
      int kbs = skb ^ (row & 7);
      glds16((const char*)(A + (size_t)grow * K + kt * BK) + kbs * 16,
             (char*)As + c * 1024);
    }
    #pragma unroll
    for (int i = 0; i < 4; ++i){
      int c = wid * 4 + i;
      int row = c * 8 + srow;
      int kbs = skb ^ (row & 7);
      glds16((const char*)(BT + ((size_t)(cb * ksteps + kt) * 128 + row) * 64) + kbs * 16,
             (char*)Bs + c * 1024);
    }
    __syncthreads();
    #pragma unroll
    for (int ks = 0; ks < 2; ++ks){
      bf16x8 af[4], bfr[4];
      #pragma unroll
      for (int m = 0; m < 4; ++m){
        int r = wm*64 + m*16 + l15;
        af[m] = *(const bf16x8*)((const char*)As + r*128 + (((ks*4 + l4) ^ (r & 7)) * 16));
      }
      #pragma unroll
      for (int n = 0; n < 4; ++n){
        int r = wn*64 + n*16 + l15;
        bfr[n] = *(const bf16x8*)((const char*)Bs + r*128 + (((ks*4 + l4) ^ (r & 7)) * 16));
      }
      #pragma unroll
      for (int m = 0; m < 4; ++m)
        #pragma unroll
        for (int n = 0; n < 4; ++n)
          acc[m][n] = __builtin_amdgcn_mfma_f32_16x16x32_bf16(af[m], bfr[n], acc[m][n], 0, 0, 0);
    }
    __syncthreads();
  }

  float bv[4]; bool val[4];
  #pragma unroll
  for (int n = 0; n < 4; ++n){
    int col = n0 + wn*64 + n*16 + l15;
    val[n] = col < N;
    bv[n] = val[n] ? bias[col] : 0.f;
  }
  #pragma unroll
  for (int m = 0; m < 4; ++m)
    #pragma unroll
    for (int q = 0; q < 4; ++q){
      int lrow = wm*64 + m*16 + l4*4 + q;
      int tr = trel_s[lrow];
      float Sl = 0.f;
      #pragma unroll
      for (int n = 0; n < 4; ++n){
        if (val[n]){
          float lg = acc[m][n][q] + bv[n];
          Sl += __expf(lg);
          int col = n0 + wn*64 + n*16 + l15;
          if (tr == col) tl[ridx[m0 + lrow]] = lg;
        }
      }
      #pragma unroll
      for (int d = 1; d < 16; d <<= 1) Sl += __shfl_xor(Sl, d);
      if (l15 == 0) reds[wn*128 + lrow] = Sl;
    }
  __syncthreads();
  if (wn == 0 && l15 == 0){
    #pragma unroll
    for (int m = 0; m < 4; ++m)
      #pragma unroll
      for (int q = 0; q < 4; ++q){
        int lrow = wm*64 + m*16 + l4*4 + q;
        P[(size_t)(m0 + lrow) * ntiles + cb] = reds[lrow] + reds[128 + lrow];
      }
  }
}

// ---------------- t2/t3: B-streaming GEMM, indirect A ---------------------
template<int NC, int BK>
__global__ __launch_bounds__(256)
void k_tail_s(const u16* __restrict__ A, const u16* __restrict__ BT,
              const float* __restrict__ bias, int N,
              float* __restrict__ P, int ntiles,
              const int* __restrict__ cnt, int bucket,
              const int* __restrict__ trel, const int* __restrict__ ridx,
              float* __restrict__ tl)
{
  constexpr int CH  = BK / 8;
  constexpr int LPR = CH;
  constexpr int RPC = 64 / LPR;
  constexpr int CPW = (128 * BK * 2 / 1024) / 4;
  const int cntv = cnt[bucket];
  const int yb = blockIdx.y, cg = blockIdx.x;
  const int m0 = yb * 128;
  if (m0 >= cntv) return;

  __shared__ u16 As[128 * BK];
  __shared__ u16 BsM[2][128 * BK];
  __shared__ float reds[2 * 128];
  __shared__ int trel_s[128];

  const int tid  = threadIdx.x;
  const int lane = tid & 63, wid = tid >> 6;
  const int wm = wid & 1, wn = wid >> 1;
  const int l15 = lane & 15, l4 = lane >> 4;
  const int srow = lane / LPR, skb = lane % LPR;

  if (tid < 128) trel_s[tid] = trel[m0 + tid];

  #pragma unroll
  for (int i = 0; i < CPW; ++i){
    int c = wid * CPW + i;
    int row = c * RPC + srow;
    int grow = (m0 + row < cntv) ? ridx[m0 + row] : ridx[0];
    int kbs = skb ^ (row & (CH - 1));
    glds16((const char*)(A + (size_t)grow * BK) + kbs * 16,
           (char*)As + c * 1024);
  }
  {
    int ci0 = cg * NC;
    if (ci0 < ntiles){
      #pragma unroll
      for (int i = 0; i < CPW; ++i){
        int c = wid * CPW + i;
        int row = c * RPC + srow;
        int kbs = skb ^ (row & (CH - 1));
        glds16((const char*)(BT + (size_t)(ci0*128 + row) * BK) + kbs * 16,
               (char*)BsM[0] + c * 1024);
      }
    }
  }
  __syncthreads();

  int buf = 0;
  for (int ct = 0; ct < NC; ++ct){
    int ci = cg * NC + ct;
    if (ci >= ntiles) break;
    if (ct + 1 < NC && ci + 1 < ntiles){
      #pragma unroll
      for (int i = 0; i < CPW; ++i){
        int c = wid * CPW + i;
        int row = c * RPC + srow;
        int kbs = skb ^ (row & (CH - 1));
        glds16((const char*)(BT + (size_t)((ci+1)*128 + row) * BK) + kbs * 16,
               (char*)BsM[buf ^ 1] + c * 1024);
      }
    }
    f32x4 acc[4][4];
    #pragma unroll
    for (int m = 0; m < 4; ++m)
      #pragma unroll
      for (int n = 0; n < 4; ++n){ acc[m][n].x=0.f; acc[m][n].y=0.f; acc[m][n].z=0.f; acc[m][n].w=0.f; }
    #pragma unroll
    for (int ks = 0; ks < BK / 32; ++ks){
      bf16x8 af[4], bfr[4];
      #pragma unroll
      for (int m = 0; m < 4; ++m){
        int r = wm*64 + m*16 + l15;
        af[m] = *(const bf16x8*)((const char*)As + r*(BK*2) + (((ks*4 + l4) ^ (r & (CH-1))) * 16));
      }
      #pragma unroll
      for (int n = 0; n < 4; ++n){
        int r = wn*64 + n*16 + l15;
        bfr[n] = *(const bf16x8*)((const char*)BsM[buf] + r*(BK*2) + (((ks*4 + l4) ^ (r & (CH-1))) * 16));
      }
      #pragma unroll
      for (int m = 0; m < 4; ++m)
        #pragma unroll
        for (int n = 0; n < 4; ++n)
          acc[m][n] = __builtin_amdgcn_mfma_f32_16x16x32_bf16(af[m], bfr[n], acc[m][n], 0, 0, 0);
    }
    const int n0 = ci * 128;
    float bv[4]; bool val[4];
    #pragma unroll
    for (int n = 0; n < 4; ++n){
      int col = n0 + wn*64 + n*16 + l15;
      val[n] = col < N;
      bv[n] = val[n] ? bias[col] : 0.f;
    }
    #pragma unroll
    for (int m = 0; m < 4; ++m)
      #pragma unroll
      for (int q = 0; q < 4; ++q){
        int lrow = wm*64 + m*16 + l4*4 + q;
        int tr = trel_s[lrow];
        float Sl = 0.f;
        #pragma unroll
        for (int n = 0; n < 4; ++n){
          if (val[n]){
            float lg = acc[m][n][q] + bv[n];
            Sl += __expf(lg);
            int col = n0 + wn*64 + n*16 + l15;
            if (tr == col) tl[ridx[m0 + lrow]] = lg;
          }
        }
        #pragma unroll
        for (int d = 1; d < 16; d <<= 1) Sl += __shfl_xor(Sl, d);
        if (l15 == 0) reds[wn*128 + lrow] = Sl;
      }
    __syncthreads();
    if (wn == 0 && l15 == 0){
      #pragma unroll
      for (int m = 0; m < 4; ++m)
        #pragma unroll
        for (int q = 0; q < 4; ++q){
          int lrow = wm*64 + m*16 + l4*4 + q;
          P[(size_t)(m0 + lrow) * ntiles + ci] = reds[lrow] + reds[128 + lrow];
        }
    }
    __syncthreads();
    buf ^= 1;
  }
}

// ---------------- final combine (P = f32 partial sums of exp) ----------------
__global__ void k_finalize(const int* __restrict__ tgt, const float* __restrict__ P,
                           const float* __restrict__ cl, const float* __restrict__ tl,
                           const int* __restrict__ pos, float* __restrict__ out)
{
  const int NT0 = 157, NT1 = 313, NT2 = 938, NT3 = 686;
  int n = blockIdx.x * 4 + (threadIdx.x >> 6);
  int lane = threadIdx.x & 63;
  int t = tgt[n];

  float s = 0.f;
  const float* p0 = P + (size_t)n * NT0;
  for (int i = lane; i < NT0; i += 64) s += p0[i];
  if (lane < 3) s += __expf(cl[n*3 + lane]);
  #pragma unroll
  for (int d = 1; d < 64; d <<= 1) s += __shfl_xor(s, d);
  float lse_head = logf(s);

  float nll;
  if (t < 20000){
    nll = lse_head - tl[n];
  } else {
    int seg, nt; size_t base;
    if      (t <  60000){ seg = 1; nt = NT1; base = (size_t)1024 * NT0; }
    else if (t < 180000){ seg = 2; nt = NT2; base = (size_t)1024 * (NT0 + NT1); }
    else                { seg = 3; nt = NT3; base = (size_t)1024 * (NT0 + NT1 + NT2); }
    float s2 = 0.f;
    const float* ps = P + base + (size_t)pos[n] * nt;
    for (int i = lane; i < nt; i += 64) s2 += ps[i];
    #pragma unroll
    for (int d = 1; d < 64; d <<= 1) s2 += __shfl_xor(s2, d);
    float lse_t = logf(s2);
    // reference quirk: bucket i uses head_lp[:, -i] == cluster logit index 3-i
    nll = lse_head - cl[n*3 + (3 - seg)] + lse_t - tl[n];
  }
  if (lane == 0) out[n] = nll;
}

// ---------------------------------------------------------------------------
extern "C" void kernel_launch(void* const* d_in, const int* in_sizes, int n_in,
                              void* d_out, int out_size, void* d_ws, size_t ws_size,
                              hipStream_t stream)
{
  const float* hidden = (const float*)d_in[0];
  const int*   target = (const int*)d_in[1];
  const float* W_head = (const float*)d_in[2];
  const float* b_head = (const float*)d_in[3];
  const float* W_clu  = (const float*)d_in[4];
  const float* b_clu  = (const float*)d_in[5];
  const float* W_p1   = (const float*)d_in[6];
  const float* W_t1   = (const float*)d_in[7];
  const float* b_t1   = (const float*)d_in[8];
  const float* W_p2   = (const float*)d_in[9];
  const float* W_t2   = (const float*)d_in[10];
  const float* b_t2   = (const float*)d_in[11];
  const float* W_p3   = (const float*)d_in[12];
  const float* W_t3   = (const float*)d_in[13];
  const float* b_t3   = (const float*)d_in[14];
  float* out = (float*)d_out;

  char* ws = (char*)d_ws;
  u16*   A0  = (u16*)(ws + 0);          // [1024][1024] bf16
  u16*   A1  = (u16*)(ws + 2097152);    // [1024][256]
  u16*   A2  = (u16*)(ws + 2621440);    // [1024][64]
  u16*   A3  = (u16*)(ws + 2752512);    // [1024][32]
  float* cl  = (float*)(ws + 2883584);  // [1024][3]
  float* tl  = (float*)(ws + 2895872);  // [1024]
  float* P   = (float*)(ws + 2899968);  // [1024][2094] f32 (8.6MB)
  u16*   BTpOv = (u16*)(ws + 2899968);  // small-ws proj overlay (sequential)
  u16*   BTh = (u16*)(ws + 11476992);   // head BT blocked [157][16][128][64]
  int*   cnt  = (int*)(ws + 52633600);
  int*   idx1 = (int*)(ws + 52633856);
  int*   idx2 = (int*)(ws + 52637952);
  int*   idx3 = (int*)(ws + 52642048);
  int*   pos  = (int*)(ws + 52646144);
  int*   trel = (int*)(ws + 52650240);  // [4096]: tr0|tr1|tr2|tr3
  int*   tr0 = trel, *tr1 = trel + 1024, *tr2 = trel + 2048, *tr3 = trel + 3072;
  u16*   BT1  = (u16*)(ws + 52666624);  // t1 blocked [313][4][128][64] (20.5MB)
  u16*   BT2  = (u16*)(ws + 73179392);  // [120064][64]  (15.4 MB)
  u16*   BT3  = (u16*)(ws + 88547584);  // [87808][32]   ( 5.6 MB)
  u16*   BTpD = (u16*)(ws + 94167296);  // dedicated proj BT [400][1024] (0.8MB)
  const size_t needA = 94986496;
  const bool bigws = ws_size >= needA;
  u16* BTp = bigws ? BTpD : BTpOv;

  float* P0  = P;
  float* Pp1 = P + (size_t)1024 * 157;
  float* Pp2 = P + (size_t)1024 * (157 + 313);
  float* Pp3 = P + (size_t)1024 * (157 + 313 + 938);

  auto addj = [](TJobs& tj, int& nb, const float* W, u16* B, int K, int N,
                 int Kpad, int nrows, int blk){
    int nx = (nrows + 63) / 64;
    int ny = (Kpad + 63) / 64;
    tj.j[tj.nj++] = TJob{W, B, K, N, Kpad, nrows, nx, nb, blk};
    nb += nx * ny;
  };

  k_init<<<16, 256, 0, stream>>>(cnt, trel);

  // ---- stage 1: proj+head transposes + cvt + compact ----
  TJobs tj{}; int nb = 0;
  addj(tj, nb, W_p1, BTp, 1024, 256, 1024, 256, 0);
  addj(tj, nb, W_p2, BTp + (size_t)256*1024, 1024, 64, 1024, 64, 0);
  addj(tj, nb, W_p3, BTp + (size_t)320*1024, 1024, 16, 1024, 16, 0);
  addj(tj, nb, W_clu, BTp + (size_t)336*1024, 1024, 3, 1024, 64, 0);
  addj(tj, nb, W_head, BTh, 1024, 20000, 1024, 20096, 1);
  k_stage1<<<nb + 512 + 4, 256, 0, stream>>>(tj, nb, 512, hidden, A0, target,
      cnt, idx1, idx2, idx3, pos, tr0, tr1, tr2, tr3);

  // proj GEMM standalone (keeps k_mega at 60 VGPR)
  k_proj_gemm<<<dim3(3, 4), 512, 0, stream>>>(A0, BTp, b_clu, A1, A2, A3, cl);

  if (bigws){
    // ---- mega: head GEMM (628 first, XCD-chunked) + tail transposes ----
    TJobs tt{}; int nbT = 0;
    addj(tt, nbT, W_t1, BT1, 256, 40000, 256, 40064, 1);
    addj(tt, nbT, W_t2, BT2, 64, 120000, 64, 120064, 0);
    addj(tt, nbT, W_t3, BT3, 16, 87735, 32, 87808, 0);
    const int gb = 157 * 4;
    k_mega<<<gb + nbT, 512, 0, stream>>>(A0, BTh, b_head, 157, P0, tr0, tl, gb, tt);

    // ---- tail GEMMs: separate launches (per-kernel regalloc) ----
    k_tail1<<<dim3(313, 8), 256, 0, stream>>>(A1, BT1, b_t1, 256, 40000,
        Pp1, 313, cnt, 0, tr1, idx1, tl);
    k_tail_s<4, 64><<<dim3(235, 8), 256, 0, stream>>>(A2, BT2, b_t2, 120000,
        Pp2, 938, cnt, 1, tr2, idx2, tl);
    k_tail_s<4, 32><<<dim3(172, 8), 256, 0, stream>>>(A3, BT3, b_t3, 87735,
        Pp3, 686, cnt, 2, tr3, idx3, tl);
  } else {
    // small ws: sequential, tails reuse BTh region
    k_gemm_lse256<<<dim3(157, 4), 512, 0, stream>>>(A0, BTh, b_head, 1024, 20000,
        P0, 157, tr0, tl);

    TJobs s1{}; int n1 = 0;
    addj(s1, n1, W_t1, BTh, 256, 40000, 256, 40064, 1);
    k_stage1<<<n1, 256, 0, stream>>>(s1, n1, 0, hidden, A0, target,
        cnt, idx1, idx2, idx3, pos, tr0, tr1, tr2, tr3);
    k_tail1<<<dim3(313, 8), 256, 0, stream>>>(A1, BTh, b_t1, 256, 40000,
        Pp1, 313, cnt, 0, tr1, idx1, tl);

    TJobs s2{}; int n2 = 0;
    addj(s2, n2, W_t2, BTh, 64, 120000, 64, 120064, 0);
    k_stage1<<<n2, 256, 0, stream>>>(s2, n2, 0, hidden, A0, target,
        cnt, idx1, idx2, idx3, pos, tr0, tr1, tr2, tr3);
    k_tail_s<4, 64><<<dim3(235, 8), 256, 0, stream>>>(A2, BTh, b_t2, 120000,
        Pp2, 938, cnt, 1, tr2, idx2, tl);

    TJobs s3{}; int n3 = 0;
    addj(s3, n3, W_t3, BTh, 16, 87735, 32, 87808, 0);
    k_stage1<<<n3, 256, 0, stream>>>(s3, n3, 0, hidden, A0, target,
        cnt, idx1, idx2, idx3, pos, tr0, tr1, tr2, tr3);
    k_tail_s<4, 32><<<dim3(172, 8), 256, 0, stream>>>(A3, BTh, b_t3, 87735,
        Pp3, 686, cnt, 2, tr3, idx3, tl);
  }

  k_finalize<<<256, 256, 0, stream>>>(target, P, cl, tl, pos, out);
}